// Round 2
// baseline (316.995 us; speedup 1.0000x reference)
//
#include <hip/hip_runtime.h>
#include <hip/hip_bf16.h>

// Problem constants (from reference)
constexpr int HH    = 1024;
constexpr int WW    = 1024;
constexpr int NPIX  = HH * WW;        // 1,048,576 pixels
constexpr int NB    = 16;             // batch replication factor
constexpr int PPT   = 4;              // pixels per thread
constexpr int BLOCK = 256;
constexpr int MAPSZ = NPIX * 3;       // floats per batch image (12.6 MiB)

// Native vector type — __builtin_nontemporal_store rejects HIP_vector_type.
typedef float vfloat4 __attribute__((ext_vector_type(4)));

// Wire dtypes (evidence R0-R3 of prior session): verts/bary f32, faces/p2f
// int32, out f32. out(n,h,w,d) is batch-invariant (reference gathers all
// batches from batch-0 face attrs; batch-0 packing offset is 0).
//
// FUSED single kernel: compute each pixel's 3-float value once, write it to
// all 16 batch images with nontemporal stores.
//   - deletes the 12.6 MiB intermediate map write of the old phase 1
//   - deletes the 15x (189 MB) map re-read of the old phase 2
//   - one launch instead of two, no inter-phase dependency stall
//
// Channel-aliasing mitigation (R4 lesson): the 12 MiB inter-batch stride is
// 3*2^22, so same-pixel copies share their low 22 address bits. Rotating the
// batch order per block ((n + blockIdx) & 15) decorrelates the instantaneous
// write footprint across resident blocks -> full channel coverage, matching
// the sequential-store pattern that hit ~6.5 TB/s in phase 2 / fillBuffer.
__global__ __launch_bounds__(BLOCK) void uv_fused(
    const float* __restrict__ verts,   // (16, 6890, 3) f32 — only batch 0 read
    const int*   __restrict__ faces,   // (13776, 3) int32
    const int*   __restrict__ p2f,     // (H, W) int32
    const float* __restrict__ bary,    // (H, W, 3) f32
    float*       __restrict__ out)     // (16, H, W, 3) f32
{
    const int t  = blockIdx.x * blockDim.x + threadIdx.x;
    const int p0 = t * PPT;                        // first pixel of this thread
    if (p0 >= NPIX) return;

    const int4 fi = *(const int4*)(p2f + p0);      // 16B aligned (16*t)
    const int fidx[PPT] = {fi.x, fi.y, fi.z, fi.w};

    const float4* b4 = (const float4*)(bary + (size_t)p0 * 3); // 48*t, aligned
    const float4 bv0 = b4[0], bv1 = b4[1], bv2 = b4[2];
    const float b[PPT * 3] = {bv0.x, bv0.y, bv0.z, bv0.w,
                              bv1.x, bv1.y, bv1.z, bv1.w,
                              bv2.x, bv2.y, bv2.z, bv2.w};

    alignas(16) float res[PPT * 3];
    #pragma unroll
    for (int i = 0; i < PPT; ++i) {
        const int f = fidx[i];
        float o0 = 0.f, o1 = 0.f, o2 = 0.f;
        if (f >= 0) {
            const int v0 = faces[3 * f + 0];
            const int v1 = faces[3 * f + 1];
            const int v2 = faces[3 * f + 2];
            const float* a0 = verts + 3 * v0;      // batch-0 slice (83 KB, L1-hot)
            const float* a1 = verts + 3 * v1;
            const float* a2 = verts + 3 * v2;
            const float w0 = b[3 * i + 0];
            const float w1 = b[3 * i + 1];
            const float w2 = b[3 * i + 2];
            o0 = w0 * a0[0] + w1 * a1[0] + w2 * a2[0];
            o1 = w0 * a0[1] + w1 * a1[1] + w2 * a2[1];
            o2 = w0 * a0[2] + w1 * a1[2] + w2 * a2[2];
        }
        res[3 * i + 0] = o0;
        res[3 * i + 1] = o1;
        res[3 * i + 2] = o2;
    }

    const vfloat4* r4 = (const vfloat4*)res;
    const vfloat4 r0 = r4[0], r1 = r4[1], r2 = r4[2];

    // Write the 3 float4s (4 pixels) to all 16 batch images, batch order
    // rotated per block to break 12 MiB power-of-two stride aliasing.
    const int rot = blockIdx.x & (NB - 1);
    float* const base = out + (size_t)p0 * 3;
    #pragma unroll
    for (int n = 0; n < NB; ++n) {
        const int bidx = (n + rot) & (NB - 1);
        vfloat4* dst = (vfloat4*)(base + (size_t)bidx * MAPSZ);
        __builtin_nontemporal_store(r0, dst + 0);  // streaming: never re-read
        __builtin_nontemporal_store(r1, dst + 1);
        __builtin_nontemporal_store(r2, dst + 2);
    }
}

extern "C" void kernel_launch(void* const* d_in, const int* in_sizes, int n_in,
                              void* d_out, int out_size, void* d_ws, size_t ws_size,
                              hipStream_t stream) {
    const float* verts = (const float*)d_in[0];   // (16, 6890, 3) f32
    const int*   faces = (const int*)d_in[1];     // (13776, 3) int32
    const int*   p2f   = (const int*)d_in[2];     // (1024, 1024) int32
    const float* bary  = (const float*)d_in[3];   // (1024, 1024, 3) f32
    float*       out   = (float*)d_out;           // (16, 1024, 1024, 3) f32

    const int grid = NPIX / PPT / BLOCK;          // 1024 blocks
    uv_fused<<<grid, BLOCK, 0, stream>>>(verts, faces, p2f, bary, out);
}

// Round 3
// 264.065 us; speedup vs baseline: 1.2004x; 1.2004x over previous
//
#include <hip/hip_runtime.h>
#include <hip/hip_bf16.h>

// Problem constants (from reference)
constexpr int HH    = 1024;
constexpr int WW    = 1024;
constexpr int NPIX  = HH * WW;        // 1,048,576 pixels
constexpr int NB    = 16;             // batch replication factor
constexpr int BLOCK = 256;
constexpr int MAPF4 = NPIX * 3 / 4;   // float4s per batch image = 786432

// Native vector type — __builtin_nontemporal_store rejects HIP_vector_type.
typedef float vfloat4 __attribute__((ext_vector_type(4)));

// Wire dtypes (evidence prior session): verts/bary f32, faces/p2f int32,
// out f32. out(n,h,w,d) is batch-invariant (reference gathers all batches
// from batch-0 face attrs; batch-0 packing offset is 0).
//
// FUSED, float4-partitioned (R2 post-mortem): R1's fused kernel stored
// 3 float4s per thread at 48 B lane stride -> each NT wave-store wrote 64B
// lines at 1/3 density -> partial-line HBM bursts -> 1.82x WRITE_SIZE
// amplification + 2.6 TB/s collapse. Fix: partition by OUTPUT FLOAT4.
// Thread j owns floats [4j, 4j+4) which span exactly 2 pixels (4 = 3+1).
// It interpolates both pixels (compute is ~free, VALUBusy 0.6%), assembles
// its float4, and NT-stores it to all 16 batch images -> every store
// instruction is 64 lanes x contiguous 16 B = dense 1 KB, full lines.
// This is exactly the store shape that hit 6.4 TB/s in the old phase 2.
__global__ __launch_bounds__(BLOCK) void uv_fused(
    const float* __restrict__ verts,   // (16, 6890, 3) f32 — only batch 0 read
    const int*   __restrict__ faces,   // (13776, 3) int32
    const int*   __restrict__ p2f,     // (H, W) int32
    const float* __restrict__ bary,    // (H, W, 3) f32
    float*       __restrict__ out)     // (16, H, W, 3) f32
{
    const int j = blockIdx.x * blockDim.x + threadIdx.x;  // global float4 idx
    if (j >= MAPF4) return;

    const int F = 4 * j;          // first float index in batch-0 map
    const int p = F / 3;          // first pixel covered
    const int c = F - 3 * p;      // component offset within pixel p (0..2)
    // floats [F, F+4) = pixel p comps [c..2] then pixel p+1 comps [0..c]

    // --- interpolate pixel p -> A[0..2], pixel p+1 -> B[0..2] ---
    float A[3] = {0.f, 0.f, 0.f};
    float B[3] = {0.f, 0.f, 0.f};

    const int f0 = p2f[p];
    const int f1 = p2f[p + 1];

    if (f0 >= 0) {
        const int v0 = faces[3 * f0 + 0];
        const int v1 = faces[3 * f0 + 1];
        const int v2 = faces[3 * f0 + 2];
        const float w0 = bary[3 * p + 0];
        const float w1 = bary[3 * p + 1];
        const float w2 = bary[3 * p + 2];
        const float* a0 = verts + 3 * v0;   // batch-0 slice (83 KB, L1-hot)
        const float* a1 = verts + 3 * v1;
        const float* a2 = verts + 3 * v2;
        #pragma unroll
        for (int d = 0; d < 3; ++d)
            A[d] = w0 * a0[d] + w1 * a1[d] + w2 * a2[d];
    }
    if (f1 >= 0) {
        const int v0 = faces[3 * f1 + 0];
        const int v1 = faces[3 * f1 + 1];
        const int v2 = faces[3 * f1 + 2];
        const float w0 = bary[3 * (p + 1) + 0];
        const float w1 = bary[3 * (p + 1) + 1];
        const float w2 = bary[3 * (p + 1) + 2];
        const float* a0 = verts + 3 * v0;
        const float* a1 = verts + 3 * v1;
        const float* a2 = verts + 3 * v2;
        #pragma unroll
        for (int d = 0; d < 3; ++d)
            B[d] = w0 * a0[d] + w1 * a1[d] + w2 * a2[d];
    }

    // assemble this thread's float4: s[k] = (c+k < 3) ? A[c+k] : B[c+k-3]
    vfloat4 r;
    #pragma unroll
    for (int k = 0; k < 4; ++k) {
        const int ck = c + k;
        r[k] = (ck < 3) ? A[ck] : B[ck - 3];
    }

    // NT-store to all 16 batch images; batch order rotated per wave to
    // decorrelate the 12 MiB (3*2^22) inter-batch stride streams.
    const int rot = (blockIdx.x * 4 + (threadIdx.x >> 6)) & (NB - 1);
    vfloat4* const base = (vfloat4*)out + j;
    #pragma unroll
    for (int n = 0; n < NB; ++n) {
        const int bidx = (n + rot) & (NB - 1);
        __builtin_nontemporal_store(r, base + (size_t)bidx * MAPF4);
    }
}

extern "C" void kernel_launch(void* const* d_in, const int* in_sizes, int n_in,
                              void* d_out, int out_size, void* d_ws, size_t ws_size,
                              hipStream_t stream) {
    const float* verts = (const float*)d_in[0];   // (16, 6890, 3) f32
    const int*   faces = (const int*)d_in[1];     // (13776, 3) int32
    const int*   p2f   = (const int*)d_in[2];     // (1024, 1024) int32
    const float* bary  = (const float*)d_in[3];   // (1024, 1024, 3) f32
    float*       out   = (float*)d_out;           // (16, 1024, 1024, 3) f32

    const int grid = (MAPF4 + BLOCK - 1) / BLOCK;  // 3072 blocks
    uv_fused<<<grid, BLOCK, 0, stream>>>(verts, faces, p2f, bary, out);
}